// Round 1
// baseline (370.709 us; speedup 1.0000x reference)
//
#include <hip/hip_runtime.h>
#include <math.h>

#define NB   32768
#define NM   2048
#define NEMB 128
#define NK   8
#define TAU  0.3f
#define FLT_BIG 3.402823466e38f

__device__ __forceinline__ float gelu_exact(float x) {
    return 0.5f * x * (1.0f + erff(x * 0.70710678118654752f));
}

// ---------------------------------------------------------------------------
// Kernel A: one wave (64 lanes) per row.
// Stream 2048 anchors (float4 = 2 anchors per lane-load), keep per-lane sorted
// top-8 (d2, ax, ay) in registers, merge across the wave with 8x argmin-pop,
// compute softmax weights, write (w, ax, ay, 0) per k to workspace.
// ---------------------------------------------------------------------------
__global__ void __launch_bounds__(256) knn_topk_kernel(
    const float* __restrict__ Gl, const float* __restrict__ ancL,
    float4* __restrict__ wsOut)
{
    const int wave = threadIdx.x >> 6;
    const int lane = threadIdx.x & 63;
    const int row  = (blockIdx.x << 2) + wave;

    const float2 g = reinterpret_cast<const float2*>(Gl)[row];
    const float4* a4 = reinterpret_cast<const float4*>(ancL) + (size_t)row * (NM / 2);

    float bd[8], bax[8], bay[8];
#pragma unroll
    for (int i = 0; i < 8; ++i) { bd[i] = FLT_BIG; bax[i] = 0.f; bay[i] = 0.f; }

    // 2048 anchors / (64 lanes * 2 per float4) = 16 iterations
#pragma unroll 4
    for (int it = 0; it < NM / 128; ++it) {
        float4 v = a4[it * 64 + lane];
#pragma unroll
        for (int h = 0; h < 2; ++h) {
            const float ax = h ? v.z : v.x;
            const float ay = h ? v.w : v.y;
            const float dx = ax - g.x, dy = ay - g.y;
            // keep bit-identical to numpy: no fma contraction
            const float d = __fadd_rn(__fmul_rn(dx, dx), __fmul_rn(dy, dy));
            if (d < bd[7]) {
                // predicated sorted insertion, static indices only
#pragma unroll
                for (int j = 7; j >= 1; --j) {
                    const bool c1 = bd[j - 1] > d;   // old values (descending j)
                    const bool c2 = bd[j] > d;
                    const float nd = c1 ? bd[j - 1] : (c2 ? d : bd[j]);
                    const float nx = c1 ? bax[j - 1] : (c2 ? ax : bax[j]);
                    const float ny = c1 ? bay[j - 1] : (c2 ? ay : bay[j]);
                    bd[j] = nd; bax[j] = nx; bay[j] = ny;
                }
                if (bd[0] > d) { bd[0] = d; bax[0] = ax; bay[0] = ay; }
            }
        }
    }

    // wave-level merge: 8x (argmin across 64 lane-heads, pop winner)
    float td[8], tax[8], tay[8];
#pragma unroll
    for (int k = 0; k < 8; ++k) {
        float d = bd[0];
        int   src = lane;
#pragma unroll
        for (int off = 32; off >= 1; off >>= 1) {
            const float od = __shfl_xor(d, off);
            const int   os = __shfl_xor(src, off);
            if (od < d || (od == d && os < src)) { d = od; src = os; }
        }
        td[k]  = d;
        tax[k] = __shfl(bax[0], src);
        tay[k] = __shfl(bay[0], src);
        if (lane == src) {
#pragma unroll
            for (int j = 0; j < 7; ++j) { bd[j] = bd[j + 1]; bax[j] = bax[j + 1]; bay[j] = bay[j + 1]; }
            bd[7] = FLT_BIG;
        }
    }

    // softmax( d2_top / TAU ): subtract max (= td[7], largest kept d2)
    const float mx = td[7];
    float ek[8], s = 0.f;
#pragma unroll
    for (int k = 0; k < 8; ++k) { ek[k] = expf((td[k] - mx) * (1.0f / TAU)); s += ek[k]; }
    const float inv = 1.0f / s;

    if (lane < 8) {
        float wv = 0.f, xv = 0.f, yv = 0.f;
#pragma unroll
        for (int k = 0; k < 8; ++k)
            if (lane == k) { wv = ek[k] * inv; xv = tax[k]; yv = tay[k]; }
        wsOut[(size_t)row * NK + lane] = make_float4(wv, xv, yv, 0.f);
    }
}

// ---------------------------------------------------------------------------
// Kernel B: one wave per row, 4 waves/block, block loops 4 row-groups.
// W2 (64 KB) staged once per block in LDS with XOR-swizzled float4 layout
// (row f, float4 slot p stored at p ^ (f & 31)) so per-lane-distinct-f
// ds_read_b128 is conflict-minimal. h1[8][128] per wave in LDS; its reads are
// same-address broadcasts across the wave (conflict-free).
// ---------------------------------------------------------------------------
__global__ void __launch_bounds__(256, 2) mlp_kernel(
    const float4* __restrict__ wsIn,
    const float* __restrict__ W1, const float* __restrict__ b1,
    const float* __restrict__ W2, const float* __restrict__ b2,
    float* __restrict__ out)
{
    __shared__ float4 w2s[NEMB * 32];        // 64 KB
    __shared__ float  h1s[4][NK][NEMB];      // 16 KB

    for (int i = threadIdx.x; i < NEMB * 32; i += 256) {
        const int f = i >> 5, p = i & 31;
        w2s[(f << 5) + (p ^ (f & 31))] = reinterpret_cast<const float4*>(W2)[i];
    }
    __syncthreads();

    const int wave = threadIdx.x >> 6;
    const int lane = threadIdx.x & 63;

    for (int itr = 0; itr < 4; ++itr) {
        const int row = itr * 8192 + (blockIdx.x << 2) + wave;

        float wk[8], axk[8], ayk[8];
#pragma unroll
        for (int k = 0; k < 8; ++k) {
            const float4 p4 = wsIn[(size_t)row * NK + k];
            wk[k] = p4.x; axk[k] = p4.y; ayk[k] = p4.z;
        }

        // layer 1: h1[k][e] = gelu(ax*W1[e][0] + ay*W1[e][1] + b1[e])
#pragma unroll
        for (int ei = 0; ei < 2; ++ei) {
            const int e = lane + (ei << 6);
            const float2 w1v = reinterpret_cast<const float2*>(W1)[e];
            const float b1v = b1[e];
#pragma unroll
            for (int k = 0; k < 8; ++k) {
                const float x = axk[k] * w1v.x + ayk[k] * w1v.y + b1v;
                h1s[wave][k][e] = gelu_exact(x);
            }
        }
        __syncthreads();

        // layer 2: lane owns f0 = lane, f1 = lane+64; 8 accumulators each
        float acc0[8], acc1[8];
#pragma unroll
        for (int k = 0; k < 8; ++k) { acc0[k] = 0.f; acc1[k] = 0.f; }
        const int f0 = lane, f1 = lane + 64;
        const int sw = lane & 31;
#pragma unroll 4
        for (int p = 0; p < 32; ++p) {
            const float4 wa = w2s[(f0 << 5) + (p ^ sw)];
            const float4 wb = w2s[(f1 << 5) + (p ^ sw)];
#pragma unroll
            for (int k = 0; k < 8; ++k) {
                const float4 h = *reinterpret_cast<const float4*>(&h1s[wave][k][p << 2]);
                acc0[k] = fmaf(h.w, wa.w, fmaf(h.z, wa.z, fmaf(h.y, wa.y, fmaf(h.x, wa.x, acc0[k]))));
                acc1[k] = fmaf(h.w, wb.w, fmaf(h.z, wb.z, fmaf(h.y, wb.y, fmaf(h.x, wb.x, acc1[k]))));
            }
        }

        // epilogue: gelu + weighted combine
        const float b2v0 = b2[f0], b2v1 = b2[f1];
        float o0 = 0.f, o1 = 0.f;
#pragma unroll
        for (int k = 0; k < 8; ++k) {
            o0 += wk[k] * gelu_exact(acc0[k] + b2v0);
            o1 += wk[k] * gelu_exact(acc1[k] + b2v1);
        }
        out[(size_t)row * NEMB + f0] = o0;
        out[(size_t)row * NEMB + f1] = o1;
        __syncthreads();  // protect h1s reuse next iteration
    }
}

extern "C" void kernel_launch(void* const* d_in, const int* in_sizes, int n_in,
                              void* d_out, int out_size, void* d_ws, size_t ws_size,
                              hipStream_t stream)
{
    const float* Gl  = (const float*)d_in[0];
    const float* anc = (const float*)d_in[1];
    const float* W1  = (const float*)d_in[2];
    const float* b1  = (const float*)d_in[3];
    const float* W2  = (const float*)d_in[4];
    const float* b2  = (const float*)d_in[5];
    float* outp = (float*)d_out;
    float4* wsb = (float4*)d_ws;   // 32768 * 8 * 16 B = 4 MiB

    knn_topk_kernel<<<NB / 4, 256, 0, stream>>>(Gl, anc, wsb);
    mlp_kernel<<<2048, 256, 0, stream>>>(wsb, W1, b1, W2, b2, outp);
}